// Round 6
// baseline (147.017 us; speedup 1.0000x reference)
//
#include <hip/hip_runtime.h>

typedef float f4 __attribute__((ext_vector_type(4)));

// Kernel 1: per-block partial SSD with FORCED 16-deep load burst.
// 2047 blocks x 256 threads x 8 float4-pairs = 4,192,256 float4 exactly.
// Inline asm emits 16 global_load_dwordx4 back-to-back with a single manual
// s_waitcnt vmcnt(0); the waitcnt asm takes every result reg as +v so the
// compiler cannot sink uses above the wait. This defeats LLVM's default
// "batch 4 loads per wait" scheduling that capped R1-R5 at ~3.3 TB/s.
__global__ __launch_bounds__(256, 4) void ssd_partials(const float* __restrict__ p,
                                                       const float* __restrict__ t,
                                                       float* __restrict__ ws) {
    const int tid = threadIdx.x;
    // Byte offset of this thread's first float4 within each 67.1 MB buffer.
    const unsigned int voff = (blockIdx.x * 2048u + tid) * 16u;
    const unsigned int o0 = voff;
    const unsigned int o1 = voff + 1u * 4096u;   // +256 float4
    const unsigned int o2 = voff + 2u * 4096u;
    const unsigned int o3 = voff + 3u * 4096u;
    const unsigned int o4 = voff + 4u * 4096u;
    const unsigned int o5 = voff + 5u * 4096u;
    const unsigned int o6 = voff + 6u * 4096u;
    const unsigned int o7 = voff + 7u * 4096u;

    f4 a0, a1, a2, a3, a4, a5, a6, a7;
    f4 b0, b1, b2, b3, b4, b5, b6, b7;

    // saddr form: global_load_dwordx4 vdst, voffset(32b VGPR), sbase(SGPR pair)
#define SSD_LD(dst, off, base) \
    asm volatile("global_load_dwordx4 %0, %1, %2" : "=v"(dst) : "v"(off), "s"(base))
    SSD_LD(a0, o0, p); SSD_LD(a1, o1, p); SSD_LD(a2, o2, p); SSD_LD(a3, o3, p);
    SSD_LD(a4, o4, p); SSD_LD(a5, o5, p); SSD_LD(a6, o6, p); SSD_LD(a7, o7, p);
    SSD_LD(b0, o0, t); SSD_LD(b1, o1, t); SSD_LD(b2, o2, t); SSD_LD(b3, o3, t);
    SSD_LD(b4, o4, t); SSD_LD(b5, o5, t); SSD_LD(b6, o6, t); SSD_LD(b7, o7, t);
#undef SSD_LD

    // One wait for all 16 loads; +v operands pin every consumer after it.
    asm volatile("s_waitcnt vmcnt(0)"
                 : "+v"(a0), "+v"(a1), "+v"(a2), "+v"(a3),
                   "+v"(a4), "+v"(a5), "+v"(a6), "+v"(a7),
                   "+v"(b0), "+v"(b1), "+v"(b2), "+v"(b3),
                   "+v"(b4), "+v"(b5), "+v"(b6), "+v"(b7));

    float acc0 = 0.f, acc1 = 0.f, acc2 = 0.f, acc3 = 0.f;
#define SSD_ACC(a, b) do {                       \
        float dx = a.x - b.x; acc0 += dx * dx;   \
        float dy = a.y - b.y; acc1 += dy * dy;   \
        float dz = a.z - b.z; acc2 += dz * dz;   \
        float dw = a.w - b.w; acc3 += dw * dw;   \
    } while (0)
    SSD_ACC(a0, b0); SSD_ACC(a1, b1); SSD_ACC(a2, b2); SSD_ACC(a3, b3);
    SSD_ACC(a4, b4); SSD_ACC(a5, b5); SSD_ACC(a6, b6); SSD_ACC(a7, b7);
#undef SSD_ACC

    float acc = (acc0 + acc1) + (acc2 + acc3);

    // wave-64 reduce
    #pragma unroll
    for (int off = 32; off > 0; off >>= 1)
        acc += __shfl_down(acc, off, 64);

    __shared__ float wave_sums[4];
    const int lane = tid & 63;
    const int wave = tid >> 6;
    if (lane == 0) wave_sums[wave] = acc;
    __syncthreads();

    if (tid == 0)
        ws[blockIdx.x] = (wave_sums[0] + wave_sums[1]) + (wave_sums[2] + wave_sums[3]);
}

// Kernel 2: reduce 2047 partials -> out[0] = sum * scale.
__global__ __launch_bounds__(256) void ssd_finalize(const float* __restrict__ ws,
                                                    float* __restrict__ out,
                                                    float scale) {
    const int tid = threadIdx.x;
    float acc = 0.f;
    #pragma unroll
    for (int k = 0; k < 8; ++k) {
        int idx = tid + k * 256;
        if (idx < 2047) acc += ws[idx];
    }

    #pragma unroll
    for (int off = 32; off > 0; off >>= 1)
        acc += __shfl_down(acc, off, 64);

    __shared__ float wave_sums[4];
    const int lane = tid & 63;
    const int wave = tid >> 6;
    if (lane == 0) wave_sums[wave] = acc;
    __syncthreads();

    if (tid == 0)
        out[0] = ((wave_sums[0] + wave_sums[1]) + (wave_sums[2] + wave_sums[3])) * scale;
}

extern "C" void kernel_launch(void* const* d_in, const int* in_sizes, int n_in,
                              void* d_out, int out_size, void* d_ws, size_t ws_size,
                              hipStream_t stream) {
    const float* pred = (const float*)d_in[0];
    const float* targ = (const float*)d_in[1];
    float* out = (float*)d_out;
    float* ws = (float*)d_ws;  // 2047 floats

    const int B = 4096;
    const int S = 2047;  // 2*d+1 with d=1023 — slice covers the whole tensor
    const float scale = 1.0f / ((float)S * (float)B);
    // total float4 = B*S*2/4 = 4,192,256 = 2047 * 2048 exactly.

    ssd_partials<<<2047, 256, 0, stream>>>(pred, targ, ws);
    ssd_finalize<<<1, 256, 0, stream>>>(ws, out, scale);
}